// Round 1
// baseline (581.875 us; speedup 1.0000x reference)
//
#include <hip/hip_runtime.h>

#define LEAKY_SLOPE 0.01f

// ---------------------------------------------------------------------------
// CSR build: histogram by dst
// ---------------------------------------------------------------------------
__global__ void count_kernel(const int* __restrict__ dst, int* __restrict__ deg, int E) {
    int i = blockIdx.x * blockDim.x + threadIdx.x;
    if (i < E) atomicAdd(&deg[dst[i]], 1);
}

// per-block sums of deg
__global__ void scan_block_sums(const int* __restrict__ deg, int* __restrict__ bsum, int n) {
    __shared__ int sdata[256];
    int i = blockIdx.x * 256 + threadIdx.x;
    int t = threadIdx.x;
    sdata[t] = (i < n) ? deg[i] : 0;
    __syncthreads();
    for (int s = 128; s > 0; s >>= 1) {
        if (t < s) sdata[t] += sdata[t + s];
        __syncthreads();
    }
    if (t == 0) bsum[blockIdx.x] = sdata[0];
}

// single-block exclusive scan of the block sums (nb <= 512)
__global__ void scan_partials(int* __restrict__ bsum, int nb, int* __restrict__ rp_end, int E) {
    __shared__ int s[512];
    int t = threadIdx.x;
    int orig = (t < nb) ? bsum[t] : 0;
    s[t] = orig;
    __syncthreads();
    for (int off = 1; off < 512; off <<= 1) {
        int v = (t >= off) ? s[t - off] : 0;
        __syncthreads();
        s[t] += v;
        __syncthreads();
    }
    if (t < nb) bsum[t] = s[t] - orig;   // exclusive
    if (t == 0) rp_end[0] = E;           // row_ptr[N] = E
}

// final scan: row_ptr, next (fill cursor), plus GCN norm terms
__global__ void scan_final(const int* __restrict__ deg, const int* __restrict__ bsum,
                           int* __restrict__ rp, int* __restrict__ next,
                           float* __restrict__ dis, float* __restrict__ swv, int n) {
    __shared__ int s[256];
    int i = blockIdx.x * 256 + threadIdx.x;
    int t = threadIdx.x;
    int orig = (i < n) ? deg[i] : 0;
    s[t] = orig;
    __syncthreads();
    for (int off = 1; off < 256; off <<= 1) {
        int v = (t >= off) ? s[t - off] : 0;
        __syncthreads();
        s[t] += v;
        __syncthreads();
    }
    if (i < n) {
        int excl = s[t] - orig + bsum[blockIdx.x];
        rp[i] = excl;
        next[i] = excl;
        float d = (float)orig + 1.0f;   // +1 self-loop
        dis[i] = rsqrtf(d);
        swv[i] = 1.0f / d;              // dis*dis
    }
}

// scatter edges into CSR order; precompute edge weight dis[src]*dis[dst]
__global__ void fill_kernel(const int* __restrict__ src, const int* __restrict__ dst,
                            const float* __restrict__ dis, int* __restrict__ next,
                            int* __restrict__ ssrc, float* __restrict__ sew, int E) {
    int e = blockIdx.x * blockDim.x + threadIdx.x;
    if (e < E) {
        int s = src[e];
        int d = dst[e];
        int pos = atomicAdd(&next[d], 1);
        ssrc[pos] = s;
        sew[pos] = dis[s] * dis[d];
    }
}

// ---------------------------------------------------------------------------
// Tall-skinny fp32 GEMM: Y[N,M] = X[N,K] @ W[K,M] (+ b)
// Block: 256 threads, 16 rows per block. W and X tile staged in LDS.
// ---------------------------------------------------------------------------
template <int K, int M, bool BIAS>
__global__ __launch_bounds__(256) void gemm_kernel(const float* __restrict__ X,
                                                   const float* __restrict__ W,
                                                   const float* __restrict__ b,
                                                   float* __restrict__ Y, int N) {
    constexpr int TR  = 16;        // rows per block
    constexpr int G   = 256 / M;   // row groups
    constexpr int RPT = TR / G;    // rows per thread
    __shared__ float Ws[K * M];
    __shared__ float Xs[TR * K];

    int tid = threadIdx.x;
    for (int i = tid * 4; i < K * M; i += 256 * 4)
        *(float4*)&Ws[i] = *(const float4*)&W[i];

    int row0 = blockIdx.x * TR;
    for (int i = tid * 4; i < TR * K; i += 256 * 4)
        *(float4*)&Xs[i] = *(const float4*)&X[(size_t)row0 * K + i];
    __syncthreads();

    int c = tid % M;
    int g = tid / M;

    float acc[RPT];
#pragma unroll
    for (int r = 0; r < RPT; ++r) acc[r] = 0.0f;

    constexpr int KC = 16;
    for (int kk = 0; kk < K; kk += KC) {
        float w[KC];
#pragma unroll
        for (int k = 0; k < KC; ++k) w[k] = Ws[(kk + k) * M + c];
#pragma unroll
        for (int r = 0; r < RPT; ++r) {
            int row = g + r * G;
#pragma unroll
            for (int k4 = 0; k4 < KC; k4 += 4) {
                float4 x4 = *(float4*)&Xs[row * K + kk + k4];
                acc[r] += x4.x * w[k4] + x4.y * w[k4 + 1] + x4.z * w[k4 + 2] + x4.w * w[k4 + 3];
            }
        }
    }

#pragma unroll
    for (int r = 0; r < RPT; ++r) {
        int row = g + r * G;
        float v = acc[r];
        if (BIAS) v += b[c];
        Y[(size_t)(row0 + row) * M + c] = v;
    }
}

// ---------------------------------------------------------------------------
// Pull aggregation: out[n,c] = sum_{e in CSR(n)} H[src[e],c]*ew[e] + H[n,c]*sw[n]
// (+ bias, + leaky relu). One wave per node, lane = channel (C=64).
// ---------------------------------------------------------------------------
template <bool RELU>
__global__ __launch_bounds__(256) void agg_kernel(const float* __restrict__ H,
                                                  const int* __restrict__ rp,
                                                  const int* __restrict__ ssrc,
                                                  const float* __restrict__ sew,
                                                  const float* __restrict__ swv,
                                                  const float* __restrict__ bias,
                                                  float* __restrict__ Yout, int n) {
    int wid  = (blockIdx.x * blockDim.x + threadIdx.x) >> 6;  // node
    int lane = threadIdx.x & 63;                              // channel
    if (wid >= n) return;

    float acc = H[(size_t)wid * 64 + lane] * swv[wid];
    int e  = rp[wid];
    int e1 = rp[wid + 1];
    for (; e + 1 < e1; e += 2) {
        int   s0 = ssrc[e],   s1 = ssrc[e + 1];
        float w0 = sew[e],    w1 = sew[e + 1];
        float h0 = H[(size_t)s0 * 64 + lane];
        float h1 = H[(size_t)s1 * 64 + lane];
        acc += h0 * w0;
        acc += h1 * w1;
    }
    if (e < e1) {
        int s = ssrc[e];
        acc += H[(size_t)s * 64 + lane] * sew[e];
    }
    if (bias) acc += bias[lane];
    if (RELU) acc = acc > 0.0f ? acc : LEAKY_SLOPE * acc;
    Yout[(size_t)wid * 64 + lane] = acc;
}

// ---------------------------------------------------------------------------
extern "C" void kernel_launch(void* const* d_in, const int* in_sizes, int n_in,
                              void* d_out, int out_size, void* d_ws, size_t ws_size,
                              hipStream_t stream) {
    const float* x   = (const float*)d_in[0];
    const int*   ei  = (const int*)d_in[1];
    const float* W1  = (const float*)d_in[2];
    const float* b1  = (const float*)d_in[3];
    const float* W2  = (const float*)d_in[4];
    const float* b2  = (const float*)d_in[5];
    const float* Wmu = (const float*)d_in[6];
    const float* bmu = (const float*)d_in[7];
    const float* Wls = (const float*)d_in[8];
    const float* bls = (const float*)d_in[9];

    const int N = in_sizes[0] / 128;   // 100000
    const int E = in_sizes[1] / 2;     // 1600000
    const int* src  = ei;
    const int* dstp = ei + E;

    auto align16 = [](size_t v) { return (v + 15) & ~(size_t)15; };
    char* ws = (char*)d_ws;
    int*   deg  = (int*)ws;   ws += align16((size_t)N * 4);
    int*   rp   = (int*)ws;   ws += align16((size_t)(N + 1) * 4);
    int*   next = (int*)ws;   ws += align16((size_t)N * 4);
    float* dis  = (float*)ws; ws += align16((size_t)N * 4);
    float* swv  = (float*)ws; ws += align16((size_t)N * 4);
    int*   bsum = (int*)ws;   ws += 4096;
    int*   ssrc = (int*)ws;   ws += align16((size_t)E * 4);
    float* sew  = (float*)ws; ws += align16((size_t)E * 4);
    float* bufA = (float*)ws; ws += (size_t)N * 64 * 4;
    float* bufB = (float*)ws; ws += (size_t)N * 64 * 4;

    float* mu = (float*)d_out;
    float* ls = mu + (size_t)N * 32;

    const int eblocks = (E + 255) / 256;
    const int nblocks = (N + 255) / 256;   // 391

    // ---- CSR build + normalization ----
    hipMemsetAsync(deg, 0, (size_t)N * sizeof(int), stream);
    count_kernel<<<eblocks, 256, 0, stream>>>(dstp, deg, E);
    scan_block_sums<<<nblocks, 256, 0, stream>>>(deg, bsum, N);
    scan_partials<<<1, 512, 0, stream>>>(bsum, nblocks, rp + N, E);
    scan_final<<<nblocks, 256, 0, stream>>>(deg, bsum, rp, next, dis, swv, N);
    fill_kernel<<<eblocks, 256, 0, stream>>>(src, dstp, dis, next, ssrc, sew, E);

    const int aggblocks = (N * 64 + 255) / 256;  // 25000

    // ---- layer 1: h1 = leaky(agg(x@W1) + b1) ----
    gemm_kernel<128, 64, false><<<N / 16, 256, 0, stream>>>(x, W1, nullptr, bufA, N);
    agg_kernel<true><<<aggblocks, 256, 0, stream>>>(bufA, rp, ssrc, sew, swv, b1, bufB, N);

    // ---- layer 2: h2 = leaky(agg(h1@W2) + b2) ----
    gemm_kernel<64, 64, false><<<N / 16, 256, 0, stream>>>(bufB, W2, nullptr, bufA, N);
    agg_kernel<true><<<aggblocks, 256, 0, stream>>>(bufA, rp, ssrc, sew, swv, b2, bufB, N);

    // ---- heads: g = agg(h2); mu = g@Wmu+bmu; ls = g@Wls+bls ----
    agg_kernel<false><<<aggblocks, 256, 0, stream>>>(bufB, rp, ssrc, sew, swv, nullptr, bufA, N);
    gemm_kernel<64, 32, true><<<N / 16, 256, 0, stream>>>(bufA, Wmu, bmu, mu, N);
    gemm_kernel<64, 32, true><<<N / 16, 256, 0, stream>>>(bufA, Wls, bls, ls, N);
}

// Round 2
// 554.781 us; speedup vs baseline: 1.0488x; 1.0488x over previous
//
#include <hip/hip_runtime.h>

#define LEAKY_SLOPE 0.01f

// ---------------------------------------------------------------------------
// CSR build: histogram by dst
// ---------------------------------------------------------------------------
__global__ void count_kernel(const int* __restrict__ dst, int* __restrict__ deg, int E) {
    int i = blockIdx.x * blockDim.x + threadIdx.x;
    if (i < E) atomicAdd(&deg[dst[i]], 1);
}

// per-block sums of deg
__global__ void scan_block_sums(const int* __restrict__ deg, int* __restrict__ bsum, int n) {
    __shared__ int sdata[256];
    int i = blockIdx.x * 256 + threadIdx.x;
    int t = threadIdx.x;
    sdata[t] = (i < n) ? deg[i] : 0;
    __syncthreads();
    for (int s = 128; s > 0; s >>= 1) {
        if (t < s) sdata[t] += sdata[t + s];
        __syncthreads();
    }
    if (t == 0) bsum[blockIdx.x] = sdata[0];
}

// single-block exclusive scan of the block sums (nb <= 512)
__global__ void scan_partials(int* __restrict__ bsum, int nb, int* __restrict__ rp_end, int E) {
    __shared__ int s[512];
    int t = threadIdx.x;
    int orig = (t < nb) ? bsum[t] : 0;
    s[t] = orig;
    __syncthreads();
    for (int off = 1; off < 512; off <<= 1) {
        int v = (t >= off) ? s[t - off] : 0;
        __syncthreads();
        s[t] += v;
        __syncthreads();
    }
    if (t < nb) bsum[t] = s[t] - orig;   // exclusive
    if (t == 0) rp_end[0] = E;           // row_ptr[N] = E
}

// final scan: row_ptr, next (fill cursor), dis = rsqrt(deg+1)
__global__ void scan_final(const int* __restrict__ deg, const int* __restrict__ bsum,
                           int* __restrict__ rp, int* __restrict__ next,
                           float* __restrict__ dis, int n) {
    __shared__ int s[256];
    int i = blockIdx.x * 256 + threadIdx.x;
    int t = threadIdx.x;
    int orig = (i < n) ? deg[i] : 0;
    s[t] = orig;
    __syncthreads();
    for (int off = 1; off < 256; off <<= 1) {
        int v = (t >= off) ? s[t - off] : 0;
        __syncthreads();
        s[t] += v;
        __syncthreads();
    }
    if (i < n) {
        int excl = s[t] - orig + bsum[blockIdx.x];
        rp[i] = excl;
        next[i] = excl;
        dis[i] = rsqrtf((float)orig + 1.0f);   // +1 self-loop
    }
}

// scatter edges into CSR order (src index only — weights are folded into dis)
__global__ void fill_kernel(const int* __restrict__ src, const int* __restrict__ dst,
                            int* __restrict__ next, int* __restrict__ ssrc, int E) {
    int e = blockIdx.x * blockDim.x + threadIdx.x;
    if (e < E) {
        int d = dst[e];
        int pos = atomicAdd(&next[d], 1);
        ssrc[pos] = src[e];
    }
}

// ---------------------------------------------------------------------------
// Tall-skinny fp32 GEMM: Y[N,M] = X[N,K] @ W[K,M] (+ b) (optionally * dis[row])
// Block: 256 threads, 16 rows per block. W and X tile staged in LDS.
// ---------------------------------------------------------------------------
template <int K, int M, bool BIAS, bool SCALE>
__global__ __launch_bounds__(256) void gemm_kernel(const float* __restrict__ X,
                                                   const float* __restrict__ W,
                                                   const float* __restrict__ b,
                                                   const float* __restrict__ dis,
                                                   float* __restrict__ Y, int N) {
    constexpr int TR  = 16;        // rows per block
    constexpr int G   = 256 / M;   // row groups
    constexpr int RPT = TR / G;    // rows per thread
    __shared__ float Ws[K * M];
    __shared__ float Xs[TR * K];

    int tid = threadIdx.x;
    for (int i = tid * 4; i < K * M; i += 256 * 4)
        *(float4*)&Ws[i] = *(const float4*)&W[i];

    int row0 = blockIdx.x * TR;
    for (int i = tid * 4; i < TR * K; i += 256 * 4)
        *(float4*)&Xs[i] = *(const float4*)&X[(size_t)row0 * K + i];
    __syncthreads();

    int c = tid % M;
    int g = tid / M;

    float acc[RPT];
#pragma unroll
    for (int r = 0; r < RPT; ++r) acc[r] = 0.0f;

    constexpr int KC = 16;
    for (int kk = 0; kk < K; kk += KC) {
        float w[KC];
#pragma unroll
        for (int k = 0; k < KC; ++k) w[k] = Ws[(kk + k) * M + c];
#pragma unroll
        for (int r = 0; r < RPT; ++r) {
            int row = g + r * G;
#pragma unroll
            for (int k4 = 0; k4 < KC; k4 += 4) {
                float4 x4 = *(float4*)&Xs[row * K + kk + k4];
                acc[r] += x4.x * w[k4] + x4.y * w[k4 + 1] + x4.z * w[k4 + 2] + x4.w * w[k4 + 3];
            }
        }
    }

#pragma unroll
    for (int r = 0; r < RPT; ++r) {
        int row = g + r * G;
        float v = acc[r];
        if (BIAS) v += b[c];
        if (SCALE) v *= dis[row0 + row];
        Y[(size_t)(row0 + row) * M + c] = v;
    }
}

// ---------------------------------------------------------------------------
// Pull aggregation over pre-scaled features Hs = H*dis:
//   out[n,c] = dis[n] * (Hs[n,c] + sum_{e in CSR(n)} Hs[src[e],c])
// (+ bias, leaky relu, optional output scale by dis[n]).
// One wave per node, lane = channel (C=64). No per-edge weights.
// ---------------------------------------------------------------------------
template <bool RELU, bool BIAS, bool SCALE_OUT>
__global__ __launch_bounds__(256) void agg_kernel(const float* __restrict__ Hs,
                                                  const int* __restrict__ rp,
                                                  const int* __restrict__ ssrc,
                                                  const float* __restrict__ dis,
                                                  const float* __restrict__ bias,
                                                  float* __restrict__ Yout, int n) {
    int wid  = (blockIdx.x * blockDim.x + threadIdx.x) >> 6;  // node
    int lane = threadIdx.x & 63;                              // channel
    if (wid >= n) return;

    float acc = Hs[(size_t)wid * 64 + lane];  // self term (dis applied at end)
    int e0 = rp[wid];
    int e1 = rp[wid + 1];
    int cnt = e1 - e0;
    const int* sp = ssrc + e0;

    int i = 0;
    float a0 = 0.0f, a1 = 0.0f;
    for (; i + 4 <= cnt; i += 4) {
        int s0 = sp[i], s1 = sp[i + 1], s2 = sp[i + 2], s3 = sp[i + 3];
        float h0 = Hs[(size_t)s0 * 64 + lane];
        float h1 = Hs[(size_t)s1 * 64 + lane];
        float h2 = Hs[(size_t)s2 * 64 + lane];
        float h3 = Hs[(size_t)s3 * 64 + lane];
        a0 += h0 + h1;
        a1 += h2 + h3;
    }
    for (; i < cnt; ++i) a0 += Hs[(size_t)sp[i] * 64 + lane];
    acc += a0 + a1;

    float d = dis[wid];
    acc *= d;
    if (BIAS) acc += bias[lane];
    if (RELU) acc = acc > 0.0f ? acc : LEAKY_SLOPE * acc;
    if (SCALE_OUT) acc *= d;
    Yout[(size_t)wid * 64 + lane] = acc;
}

// ---------------------------------------------------------------------------
extern "C" void kernel_launch(void* const* d_in, const int* in_sizes, int n_in,
                              void* d_out, int out_size, void* d_ws, size_t ws_size,
                              hipStream_t stream) {
    const float* x   = (const float*)d_in[0];
    const int*   ei  = (const int*)d_in[1];
    const float* W1  = (const float*)d_in[2];
    const float* b1  = (const float*)d_in[3];
    const float* W2  = (const float*)d_in[4];
    const float* b2  = (const float*)d_in[5];
    const float* Wmu = (const float*)d_in[6];
    const float* bmu = (const float*)d_in[7];
    const float* Wls = (const float*)d_in[8];
    const float* bls = (const float*)d_in[9];

    const int N = in_sizes[0] / 128;   // 100000
    const int E = in_sizes[1] / 2;     // 1600000
    const int* src  = ei;
    const int* dstp = ei + E;

    auto align16 = [](size_t v) { return (v + 15) & ~(size_t)15; };
    char* ws = (char*)d_ws;
    int*   deg  = (int*)ws;   ws += align16((size_t)N * 4);
    int*   rp   = (int*)ws;   ws += align16((size_t)(N + 1) * 4);
    int*   next = (int*)ws;   ws += align16((size_t)N * 4);
    float* dis  = (float*)ws; ws += align16((size_t)N * 4);
    int*   bsum = (int*)ws;   ws += 4096;
    int*   ssrc = (int*)ws;   ws += align16((size_t)E * 4);
    float* bufA = (float*)ws; ws += (size_t)N * 64 * 4;
    float* bufB = (float*)ws; ws += (size_t)N * 64 * 4;

    float* mu = (float*)d_out;
    float* ls = mu + (size_t)N * 32;

    const int eblocks = (E + 255) / 256;
    const int nblocks = (N + 255) / 256;   // 391

    // ---- CSR build + normalization ----
    hipMemsetAsync(deg, 0, (size_t)N * sizeof(int), stream);
    count_kernel<<<eblocks, 256, 0, stream>>>(dstp, deg, E);
    scan_block_sums<<<nblocks, 256, 0, stream>>>(deg, bsum, N);
    scan_partials<<<1, 512, 0, stream>>>(bsum, nblocks, rp + N, E);
    scan_final<<<nblocks, 256, 0, stream>>>(deg, bsum, rp, next, dis, N);
    fill_kernel<<<eblocks, 256, 0, stream>>>(src, dstp, next, ssrc, E);

    const int aggblocks = (N * 64 + 255) / 256;  // 25000

    // ---- layer 1: Hs1 = (x@W1)*dis ; h1 = leaky(dis*(Hs1[n]+sum) + b1) ----
    gemm_kernel<128, 64, false, true><<<N / 16, 256, 0, stream>>>(x, W1, nullptr, dis, bufA, N);
    agg_kernel<true, true, false><<<aggblocks, 256, 0, stream>>>(bufA, rp, ssrc, dis, b1, bufB, N);

    // ---- layer 2: Hs2 = (h1@W2)*dis ; h2s = leaky(dis*(..)+b2)*dis ----
    gemm_kernel<64, 64, false, true><<<N / 16, 256, 0, stream>>>(bufB, W2, nullptr, dis, bufA, N);
    agg_kernel<true, true, true><<<aggblocks, 256, 0, stream>>>(bufA, rp, ssrc, dis, b2, bufB, N);

    // ---- heads: g = dis*(h2s[n]+sum h2s[src]) ; mu = g@Wmu+bmu ; ls = g@Wls+bls
    agg_kernel<false, false, false><<<aggblocks, 256, 0, stream>>>(bufB, rp, ssrc, dis, nullptr, bufA, N);
    gemm_kernel<64, 32, true, false><<<N / 16, 256, 0, stream>>>(bufA, Wmu, bmu, nullptr, mu, N);
    gemm_kernel<64, 32, true, false><<<N / 16, 256, 0, stream>>>(bufA, Wls, bls, nullptr, ls, N);
}

// Round 3
// 526.786 us; speedup vs baseline: 1.1046x; 1.0531x over previous
//
#include <hip/hip_runtime.h>

#define LEAKY_SLOPE 0.01f

__device__ __forceinline__ unsigned short f2bf(float f) {
    unsigned int u = __builtin_bit_cast(unsigned int, f);
    u = (u + 0x7FFFu + ((u >> 16) & 1u)) >> 16;   // round-to-nearest-even
    return (unsigned short)u;
}
__device__ __forceinline__ float bf2f(unsigned short h) {
    return __builtin_bit_cast(float, ((unsigned int)h) << 16);
}

// ---------------------------------------------------------------------------
// CSR build: histogram by dst
// ---------------------------------------------------------------------------
__global__ void count_kernel(const int* __restrict__ dst, int* __restrict__ deg, int E) {
    int i = blockIdx.x * blockDim.x + threadIdx.x;
    if (i < E) atomicAdd(&deg[dst[i]], 1);
}

__global__ void scan_block_sums(const int* __restrict__ deg, int* __restrict__ bsum, int n) {
    __shared__ int sdata[256];
    int i = blockIdx.x * 256 + threadIdx.x;
    int t = threadIdx.x;
    sdata[t] = (i < n) ? deg[i] : 0;
    __syncthreads();
    for (int s = 128; s > 0; s >>= 1) {
        if (t < s) sdata[t] += sdata[t + s];
        __syncthreads();
    }
    if (t == 0) bsum[blockIdx.x] = sdata[0];
}

__global__ void scan_partials(int* __restrict__ bsum, int nb, int* __restrict__ rp_end, int E) {
    __shared__ int s[512];
    int t = threadIdx.x;
    int orig = (t < nb) ? bsum[t] : 0;
    s[t] = orig;
    __syncthreads();
    for (int off = 1; off < 512; off <<= 1) {
        int v = (t >= off) ? s[t - off] : 0;
        __syncthreads();
        s[t] += v;
        __syncthreads();
    }
    if (t < nb) bsum[t] = s[t] - orig;   // exclusive
    if (t == 0) rp_end[0] = E;           // row_ptr[N] = E
}

__global__ void scan_final(const int* __restrict__ deg, const int* __restrict__ bsum,
                           int* __restrict__ rp, int* __restrict__ next,
                           float* __restrict__ dis, int n) {
    __shared__ int s[256];
    int i = blockIdx.x * 256 + threadIdx.x;
    int t = threadIdx.x;
    int orig = (i < n) ? deg[i] : 0;
    s[t] = orig;
    __syncthreads();
    for (int off = 1; off < 256; off <<= 1) {
        int v = (t >= off) ? s[t - off] : 0;
        __syncthreads();
        s[t] += v;
        __syncthreads();
    }
    if (i < n) {
        int excl = s[t] - orig + bsum[blockIdx.x];
        rp[i] = excl;
        next[i] = excl;
        dis[i] = rsqrtf((float)orig + 1.0f);   // +1 self-loop
    }
}

// ---------------------------------------------------------------------------
// Fused: blocks [0,GB) compute Hs1 = (X@W1)*dis -> bf16; blocks [GB,GB+EB)
// scatter edges into CSR order. gemm1's ~35us hides under fill's latency.
// LDS kept to 8KB (X tile only; W read through L1) so fill occupancy survives.
// ---------------------------------------------------------------------------
__global__ __launch_bounds__(256) void gemm1_fill_kernel(
    const float* __restrict__ X, const float* __restrict__ W,
    const float* __restrict__ dis, unsigned short* __restrict__ Hh,
    const int* __restrict__ src, const int* __restrict__ dst,
    int* __restrict__ next, int* __restrict__ ssrc, int GB, int E) {
    if ((int)blockIdx.x >= GB) {
        int e = ((int)blockIdx.x - GB) * 256 + threadIdx.x;
        if (e < E) {
            int d = dst[e];
            int pos = atomicAdd(&next[d], 1);
            __builtin_nontemporal_store(src[e], &ssrc[pos]);
        }
        return;
    }
    __shared__ float Xs[16 * 128];
    int tid = threadIdx.x;
    int row0 = blockIdx.x * 16;
    for (int i = tid * 4; i < 16 * 128; i += 256 * 4)
        *(float4*)&Xs[i] = *(const float4*)&X[(size_t)row0 * 128 + i];
    __syncthreads();

    int c = tid & 63;
    int g = tid >> 6;   // 4 row-groups; rows g, g+4, g+8, g+12
    float acc[4] = {0.f, 0.f, 0.f, 0.f};
    for (int kk = 0; kk < 128; kk += 16) {
        float w[16];
#pragma unroll
        for (int k = 0; k < 16; ++k) w[k] = W[(kk + k) * 64 + c];
#pragma unroll
        for (int r = 0; r < 4; ++r) {
            int row = g + r * 4;
#pragma unroll
            for (int k4 = 0; k4 < 16; k4 += 4) {
                float4 x4 = *(float4*)&Xs[row * 128 + kk + k4];
                acc[r] += x4.x * w[k4] + x4.y * w[k4 + 1] + x4.z * w[k4 + 2] + x4.w * w[k4 + 3];
            }
        }
    }
#pragma unroll
    for (int r = 0; r < 4; ++r) {
        int row = row0 + g + r * 4;
        Hh[(size_t)row * 64 + c] = f2bf(acc[r] * dis[row]);
    }
}

// ---------------------------------------------------------------------------
// Gather macro body: acc = self + sum of bf16 neighbor rows (fp32 accumulate)
// ---------------------------------------------------------------------------
#define GATHER_BODY(Hh, wid, lane)                                            \
    float acc = bf2f(Hh[(size_t)(wid) * 64 + (lane)]);                        \
    {                                                                         \
        int e0 = rp[wid], e1 = rp[(wid) + 1];                                 \
        const int* sp = ssrc + e0;                                            \
        int cnt = e1 - e0;                                                    \
        int i = 0;                                                            \
        float a0 = 0.f, a1 = 0.f;                                             \
        for (; i + 4 <= cnt; i += 4) {                                        \
            int s0 = sp[i], s1 = sp[i + 1], s2 = sp[i + 2], s3 = sp[i + 3];   \
            float h0 = bf2f(Hh[(size_t)s0 * 64 + (lane)]);                    \
            float h1v = bf2f(Hh[(size_t)s1 * 64 + (lane)]);                   \
            float h2v = bf2f(Hh[(size_t)s2 * 64 + (lane)]);                   \
            float h3v = bf2f(Hh[(size_t)s3 * 64 + (lane)]);                   \
            a0 += h0 + h1v;                                                   \
            a1 += h2v + h3v;                                                  \
        }                                                                     \
        for (; i < cnt; ++i) a0 += bf2f(Hh[(size_t)sp[i] * 64 + (lane)]);     \
        acc += a0 + a1;                                                       \
    }

// ---------------------------------------------------------------------------
// aggA: h1 = leaky(dis*agg(Hs1) + b1); Hs2 = (h1 @ W2)*dis -> bf16
// W2 column held in 64 VGPRs/lane; h1 broadcast via v_readlane (VALU, hides
// under gather latency). One wave per node, grid-stride.
// ---------------------------------------------------------------------------
__global__ __launch_bounds__(256) void aggA_kernel(
    const unsigned short* __restrict__ Hh, const int* __restrict__ rp,
    const int* __restrict__ ssrc, const float* __restrict__ dis,
    const float* __restrict__ b1, const float* __restrict__ W2,
    unsigned short* __restrict__ Oh, int n) {
    int lane = threadIdx.x & 63;
    float wc[64];
#pragma unroll
    for (int k = 0; k < 64; ++k) wc[k] = W2[k * 64 + lane];
    float bias = b1[lane];

    int wid = (int)((blockIdx.x * blockDim.x + threadIdx.x) >> 6);
    int nwaves = (int)((gridDim.x * blockDim.x) >> 6);
    for (; wid < n; wid += nwaves) {
        GATHER_BODY(Hh, wid, lane)
        float d = dis[wid];
        float h = fmaf(acc, d, bias);
        h = h > 0.f ? h : LEAKY_SLOPE * h;
        int hb = __builtin_bit_cast(int, h);
        float o = 0.f;
#pragma unroll
        for (int k = 0; k < 64; ++k) {
            float hk = __builtin_bit_cast(float, __builtin_amdgcn_readlane(hb, k));
            o = fmaf(hk, wc[k], o);
        }
        Oh[(size_t)wid * 64 + lane] = f2bf(o * d);
    }
}

// ---------------------------------------------------------------------------
// aggB: h2 = leaky(dis*agg(Hs2) + b2); h2s = h2*dis -> bf16
// ---------------------------------------------------------------------------
__global__ __launch_bounds__(256) void aggB_kernel(
    const unsigned short* __restrict__ Hh, const int* __restrict__ rp,
    const int* __restrict__ ssrc, const float* __restrict__ dis,
    const float* __restrict__ b2, unsigned short* __restrict__ Oh, int n) {
    int lane = threadIdx.x & 63;
    float bias = b2[lane];
    int wid = (int)((blockIdx.x * blockDim.x + threadIdx.x) >> 6);
    int nwaves = (int)((gridDim.x * blockDim.x) >> 6);
    for (; wid < n; wid += nwaves) {
        GATHER_BODY(Hh, wid, lane)
        float d = dis[wid];
        float h = fmaf(acc, d, bias);
        h = h > 0.f ? h : LEAKY_SLOPE * h;
        Oh[(size_t)wid * 64 + lane] = f2bf(h * d);
    }
}

// ---------------------------------------------------------------------------
// aggC: g = dis*agg(h2s); mu = g@Wmu + bmu; ls = g@Wls + bls -> d_out
// lanes 0-31 own mu channels, lanes 32-63 own ls channels.
// ---------------------------------------------------------------------------
__global__ __launch_bounds__(256) void aggC_kernel(
    const unsigned short* __restrict__ Hh, const int* __restrict__ rp,
    const int* __restrict__ ssrc, const float* __restrict__ dis,
    const float* __restrict__ Wmu, const float* __restrict__ bmu,
    const float* __restrict__ Wls, const float* __restrict__ bls,
    float* __restrict__ mu, float* __restrict__ ls, int n) {
    int lane = threadIdx.x & 63;
    int half = lane >> 5;
    int c = lane & 31;
    const float* Wp = half ? Wls : Wmu;
    float wc[64];
#pragma unroll
    for (int k = 0; k < 64; ++k) wc[k] = Wp[k * 32 + c];
    float bias = half ? bls[c] : bmu[c];
    float* outp = half ? ls : mu;

    int wid = (int)((blockIdx.x * blockDim.x + threadIdx.x) >> 6);
    int nwaves = (int)((gridDim.x * blockDim.x) >> 6);
    for (; wid < n; wid += nwaves) {
        GATHER_BODY(Hh, wid, lane)
        float gval = acc * dis[wid];
        int gb = __builtin_bit_cast(int, gval);
        float o = bias;
#pragma unroll
        for (int k = 0; k < 64; ++k) {
            float gk = __builtin_bit_cast(float, __builtin_amdgcn_readlane(gb, k));
            o = fmaf(gk, wc[k], o);
        }
        outp[(size_t)wid * 32 + c] = o;
    }
}

// ---------------------------------------------------------------------------
extern "C" void kernel_launch(void* const* d_in, const int* in_sizes, int n_in,
                              void* d_out, int out_size, void* d_ws, size_t ws_size,
                              hipStream_t stream) {
    const float* x   = (const float*)d_in[0];
    const int*   ei  = (const int*)d_in[1];
    const float* W1  = (const float*)d_in[2];
    const float* b1  = (const float*)d_in[3];
    const float* W2  = (const float*)d_in[4];
    const float* b2  = (const float*)d_in[5];
    const float* Wmu = (const float*)d_in[6];
    const float* bmu = (const float*)d_in[7];
    const float* Wls = (const float*)d_in[8];
    const float* bls = (const float*)d_in[9];

    const int N = in_sizes[0] / 128;   // 100000
    const int E = in_sizes[1] / 2;     // 1600000
    const int* src  = ei;
    const int* dstp = ei + E;

    auto align16 = [](size_t v) { return (v + 15) & ~(size_t)15; };
    char* ws = (char*)d_ws;
    int*   deg  = (int*)ws;   ws += align16((size_t)N * 4);
    int*   rp   = (int*)ws;   ws += align16((size_t)(N + 1) * 4);
    int*   next = (int*)ws;   ws += align16((size_t)N * 4);
    float* dis  = (float*)ws; ws += align16((size_t)N * 4);
    int*   bsum = (int*)ws;   ws += 4096;
    int*   ssrc = (int*)ws;   ws += align16((size_t)E * 4);
    unsigned short* bufH0 = (unsigned short*)ws; ws += align16((size_t)N * 64 * 2);
    unsigned short* bufH1 = (unsigned short*)ws; ws += align16((size_t)N * 64 * 2);

    float* mu = (float*)d_out;
    float* ls = mu + (size_t)N * 32;

    const int eblocks = (E + 255) / 256;   // 6250
    const int nblocks = (N + 255) / 256;   // 391
    const int GB = N / 16;                 // 6250 gemm blocks

    // ---- CSR build + normalization ----
    hipMemsetAsync(deg, 0, (size_t)N * sizeof(int), stream);
    count_kernel<<<eblocks, 256, 0, stream>>>(dstp, deg, E);
    scan_block_sums<<<nblocks, 256, 0, stream>>>(deg, bsum, N);
    scan_partials<<<1, 512, 0, stream>>>(bsum, nblocks, rp + N, E);
    scan_final<<<nblocks, 256, 0, stream>>>(deg, bsum, rp, next, dis, N);

    // ---- Hs1 = (x@W1)*dis (bf16)  ||  CSR fill ----
    gemm1_fill_kernel<<<GB + eblocks, 256, 0, stream>>>(x, W1, dis, bufH0,
                                                        src, dstp, next, ssrc, GB, E);

    const int aggblocks = 2048;  // 8192 waves, grid-stride

    // ---- layer1 agg + W2 matvec -> Hs2 ----
    aggA_kernel<<<aggblocks, 256, 0, stream>>>(bufH0, rp, ssrc, dis, b1, W2, bufH1, N);
    // ---- layer2 agg -> h2s ----
    aggB_kernel<<<aggblocks, 256, 0, stream>>>(bufH1, rp, ssrc, dis, b2, bufH0, N);
    // ---- head agg + dual matvec -> mu, ls ----
    aggC_kernel<<<aggblocks, 256, 0, stream>>>(bufH0, rp, ssrc, dis, Wmu, bmu,
                                               Wls, bls, mu, ls, N);
}